// Round 6
// baseline (661.426 us; speedup 1.0000x reference)
//
#include <hip/hip_runtime.h>
#include <hip/hip_bf16.h>
#include <cstdint>

// patch_tokens [8,1024,768] f32, vocab [30000,512] f32, W1 [512,768], gamma/beta [768],
// W2 [768,768], b2 [768]  ->  out [8,30000] f32 (softmax mixture weights)

#define CDIV(a,b) (((a)+(b)-1)/(b))

using bf16x8 = __attribute__((ext_vector_type(8))) __bf16;
using f32x4  = __attribute__((ext_vector_type(4))) float;
using f32x16 = __attribute__((ext_vector_type(16))) float;
using u16x8  = __attribute__((ext_vector_type(8))) unsigned short;
using u32x4  = __attribute__((ext_vector_type(4))) unsigned;

__device__ __forceinline__ unsigned short f2bf(float x) {
  unsigned u = __float_as_uint(x);
  u += 0x7fffu + ((u >> 16) & 1u);          // round-to-nearest-even
  return (unsigned short)(u >> 16);
}
__device__ __forceinline__ float bf2f(unsigned short b) {
  return __uint_as_float(((unsigned)b) << 16);
}
// order-preserving float<->uint key for atomicMax
__device__ __forceinline__ unsigned fkey(float x) {
  unsigned u = __float_as_uint(x);
  return (u & 0x80000000u) ? ~u : (u | 0x80000000u);
}
__device__ __forceinline__ float fdec(unsigned k) {
  unsigned u = (k & 0x80000000u) ? (k ^ 0x80000000u) : ~k;
  return __uint_as_float(u);
}

// ---------------------------------------------------------------------------
// BIG GEMM, 256x256 tile, 32x32x16 MFMA, 2 phases per K-tile (T1..T5).
// C[m][n] = sum_k A[m][k]*B[n][k]; A=[8192][768], B=[30208][768] bf16.
// Epilogue: column max over 256 rows, * rnorm[col], atomicMax maxk[b][col].
// LDS layout/swizzle identical to the verified 16x16 version (conflicts==0):
// region(slot,mat,khalf)=[256][32] bf16, chunk ^= (row>>1)&3.
// Pipeline: 2 stage-calls per phase, 6 half-tiles ahead, vmcnt(8) per phase.
// ---------------------------------------------------------------------------
template<int NT, int NXT, int CPX>
__global__ __launch_bounds__(512, 1)
void gemm8p32_kernel(const unsigned short* __restrict__ A,
                     const unsigned short* __restrict__ B,
                     const float* __restrict__ rnorm,
                     unsigned* __restrict__ maxk)
{
  constexpr int K = NT * 64;
  __shared__ __align__(16) unsigned short lds[8 * 8192];  // 128 KiB

  const int tid = threadIdx.x;
  const int w = tid >> 6, lane = tid & 63;
  const int l31 = lane & 31, lh = lane >> 5;   // row-in-tile, k-group
  const int wr = w >> 2, wc = w & 3;           // 2 x 4 wave grid

  const int bid = blockIdx.x;
  const int wg = CPX ? ((bid & 7) * CPX + (bid >> 3)) : bid;
  const long m0 = (long)(wg / NXT) * 256;
  const long n0 = (long)(wg % NXT) * 256;

  auto stage = [&](int slot, int tk, int mat, int h) {
    const unsigned short* src = mat ? B : A;
    const long row0 = mat ? n0 : m0;
    unsigned short* dst = lds + (((slot * 2) + mat) * 2 + h) * 8192;
#pragma unroll
    for (int ld = 0; ld < 2; ++ld) {
      const int lc  = ld * 512 + tid;
      const long row = row0 + (lc >> 2);
      const int qc  = (lc & 3) ^ (((lc >> 2) >> 1) & 3);
      const unsigned short* gp = src + row * K + tk * 64 + h * 32 + qc * 8;
      __builtin_amdgcn_global_load_lds(
          (const __attribute__((address_space(1))) void*)gp,
          (__attribute__((address_space(3))) void*)(dst + (ld * 512 + (w << 6)) * 8),
          16, 0, 0);
    }
  };
  // 32x32x16 A-frag: row = wr*128 + mt*32 + l31, k-chunk = ks*2 + lh
  auto rdA = [&](int s, int h, int mt, int ks) -> bf16x8 {
    const int row = wr * 128 + mt * 32 + l31;
    const int pc  = (ks * 2 + lh) ^ ((row >> 1) & 3);
    return *(const bf16x8*)(lds + ((s * 2 + 0) * 2 + h) * 8192 + row * 32 + pc * 8);
  };
  auto rdB = [&](int s, int h, int nt, int ks) -> bf16x8 {
    const int row = wc * 64 + nt * 32 + l31;
    const int pc  = (ks * 2 + lh) ^ ((row >> 1) & 3);
    return *(const bf16x8*)(lds + ((s * 2 + 1) * 2 + h) * 8192 + row * 32 + pc * 8);
  };

  f32x16 acc[4][2];
#pragma unroll
  for (int i = 0; i < 4; ++i)
#pragma unroll
    for (int j = 0; j < 2; ++j)
#pragma unroll
      for (int e = 0; e < 16; ++e) acc[i][j][e] = 0.f;

  // prologue: tile0 complete + tile1 k-half0  (6 stage calls = 12 loads)
  stage(0, 0, 0, 0); stage(0, 0, 1, 0); stage(0, 0, 0, 1);
  stage(0, 0, 1, 1); stage(1, 1, 0, 0); stage(1, 1, 1, 0);
  asm volatile("s_waitcnt vmcnt(8)" ::: "memory");
  __builtin_amdgcn_s_barrier();

  bf16x8 a[4][2], b[2][2];
  auto phase = [&](int s, int h, int st_slot, int st_tk, int st_h) {
#pragma unroll
    for (int mt = 0; mt < 4; ++mt)
#pragma unroll
      for (int ks = 0; ks < 2; ++ks) a[mt][ks] = rdA(s, h, mt, ks);
#pragma unroll
    for (int nt = 0; nt < 2; ++nt)
#pragma unroll
      for (int ks = 0; ks < 2; ++ks) b[nt][ks] = rdB(s, h, nt, ks);
    stage(st_slot, st_tk, 0, st_h);
    stage(st_slot, st_tk, 1, st_h);
    __builtin_amdgcn_s_barrier();
    asm volatile("s_waitcnt lgkmcnt(0)" ::: "memory");
    __builtin_amdgcn_sched_barrier(0);
    __builtin_amdgcn_s_setprio(1);
#pragma unroll
    for (int mt = 0; mt < 4; ++mt)
#pragma unroll
      for (int nt = 0; nt < 2; ++nt)
#pragma unroll
        for (int ks = 0; ks < 2; ++ks)
          acc[mt][nt] = __builtin_amdgcn_mfma_f32_32x32x16_bf16(
              a[mt][ks], b[nt][ks], acc[mt][nt], 0, 0, 0);
    __builtin_amdgcn_s_setprio(0);
    asm volatile("s_waitcnt vmcnt(8)" ::: "memory");
    __builtin_amdgcn_sched_barrier(0);
    __builtin_amdgcn_s_barrier();
  };

  for (int tt = 0; tt < NT; tt += 2) {
#pragma unroll
    for (int u = 0; u < 2; ++u) {
      const int t = tt + u, s = u;
      const int t1c = (t + 1 < NT) ? t + 1 : NT - 1;
      const int t2c = (t + 2 < NT) ? t + 2 : NT - 1;
      // phase A: k-half 0; stage (t+1).k1 into s^1
      phase(s, 0, s ^ 1, t1c, 1);
      // phase B: k-half 1; stage (t+2).k0 into s (its k0 reads are done)
      phase(s, 1, s, t2c, 0);
    }
  }

  // epilogue: column max over the wave's 128 rows, scale by rnorm, atomicMax.
  // C/D map: col = l31 (+nt*32), row = (reg&3)+8*(reg>>2)+4*lh (+mt*32).
  const int bb = (int)(m0 >> 10);   // 256 | 1024: tile never straddles batches
  float mx[2];
#pragma unroll
  for (int nt = 0; nt < 2; ++nt) {
    float m = acc[0][nt][0];
#pragma unroll
    for (int mt = 0; mt < 4; ++mt)
#pragma unroll
      for (int e = 0; e < 16; ++e) m = fmaxf(m, acc[mt][nt][e]);
    m = fmaxf(m, __shfl_xor(m, 32));   // combine the two lh row-subsets
    mx[nt] = m;
  }
  if (lane < 32) {
#pragma unroll
    for (int nt = 0; nt < 2; ++nt) {
      const long gn = n0 + wc * 64 + nt * 32 + l31;
      atomicMax(maxk + (long)bb * 30208 + gn, fkey(mx[nt] * rnorm[gn]));
    }
  }
}

// ---------------------------------------------------------------------------
// Unified 8-phase 256x256 NT GEMM, 16x16x32 MFMA (verified) for small GEMMs.
// EPI 0: store bf16 C + fused BN column stats (guard gm<=aclamp)
// EPI 1: store bf16 (C+bias) + fused per-row sumsq -> atomicAdd faux[row]
// ---------------------------------------------------------------------------
template<int NT, int NXT, int EPI>
__global__ __launch_bounds__(512, 1)
void gemm8p_kernel(const unsigned short* __restrict__ A,
                   const unsigned short* __restrict__ B,
                   unsigned short* __restrict__ Cout,
                   const float* __restrict__ bias,
                   float* __restrict__ faux,
                   int aclamp)
{
  constexpr int K = NT * 64;
  __shared__ __align__(16) unsigned short lds[8 * 8192];  // 128 KiB

  const int tid = threadIdx.x;
  const int w = tid >> 6, lane = tid & 63;
  const int lr = lane & 15, kg = lane >> 4;
  const int wr = w >> 2, wc = w & 3;

  const int wg = blockIdx.x;
  const long m0 = (long)(wg / NXT) * 256;
  const long n0 = (long)(wg % NXT) * 256;

  auto stage = [&](int slot, int tk, int mat, int h) {
    const unsigned short* src = mat ? B : A;
    const long row0 = mat ? n0 : m0;
    unsigned short* dst = lds + (((slot * 2) + mat) * 2 + h) * 8192;
#pragma unroll
    for (int ld = 0; ld < 2; ++ld) {
      const int lc  = ld * 512 + tid;
      long row = row0 + (lc >> 2);
      if (!mat && row > aclamp) row = aclamp;
      const int qc  = (lc & 3) ^ (((lc >> 2) >> 1) & 3);
      const unsigned short* gp = src + row * K + tk * 64 + h * 32 + qc * 8;
      __builtin_amdgcn_global_load_lds(
          (const __attribute__((address_space(1))) void*)gp,
          (__attribute__((address_space(3))) void*)(dst + (ld * 512 + (w << 6)) * 8),
          16, 0, 0);
    }
  };
  auto rdA = [&](int s, int h, int fm) -> bf16x8 {
    const int row = wr * 128 + fm * 16 + lr;
    const int pc  = kg ^ ((row >> 1) & 3);
    return *(const bf16x8*)(lds + ((s * 2 + 0) * 2 + h) * 8192 + row * 32 + pc * 8);
  };
  auto rdB = [&](int s, int h, int fn) -> bf16x8 {
    const int row = wc * 64 + fn * 16 + lr;
    const int pc  = kg ^ ((row >> 1) & 3);
    return *(const bf16x8*)(lds + ((s * 2 + 1) * 2 + h) * 8192 + row * 32 + pc * 8);
  };

  f32x4 acc[8][4];
#pragma unroll
  for (int i = 0; i < 8; ++i)
#pragma unroll
    for (int j = 0; j < 4; ++j) acc[i][j] = f32x4{0.f, 0.f, 0.f, 0.f};

  stage(0, 0, 0, 0); stage(0, 0, 1, 0); stage(0, 0, 0, 1);
  stage(0, 0, 1, 1); stage(1, 1, 0, 0); stage(1, 1, 1, 0);
  asm volatile("s_waitcnt vmcnt(8)" ::: "memory");
  __builtin_amdgcn_s_barrier();

  bf16x8 a[4], b[4];
  auto tile_body = [&](int t, int s) {
    const int t1c = (t + 1 < NT) ? t + 1 : NT - 1;
    const int t2c = (t + 2 < NT) ? t + 2 : NT - 1;
    const int s1  = s ^ 1;

    // ---- P0: k-half 0, m-half 0 ----
#pragma unroll
    for (int i = 0; i < 4; ++i) a[i] = rdA(s, 0, i);
#pragma unroll
    for (int i = 0; i < 4; ++i) b[i] = rdB(s, 0, i);
    stage(s1, t1c, 0, 1);
    __builtin_amdgcn_s_barrier();
    asm volatile("s_waitcnt lgkmcnt(0)" ::: "memory");
    __builtin_amdgcn_sched_barrier(0);
    __builtin_amdgcn_s_setprio(1);
#pragma unroll
    for (int fm = 0; fm < 4; ++fm)
#pragma unroll
      for (int fn = 0; fn < 4; ++fn)
        acc[fm][fn] = __builtin_amdgcn_mfma_f32_16x16x32_bf16(a[fm], b[fn], acc[fm][fn], 0, 0, 0);
    __builtin_amdgcn_s_setprio(0);
    __builtin_amdgcn_sched_barrier(0);
    __builtin_amdgcn_s_barrier();

    // ---- P1: k-half 0, m-half 1 ----
#pragma unroll
    for (int i = 0; i < 4; ++i) a[i] = rdA(s, 0, 4 + i);
    stage(s1, t1c, 1, 1);
    __builtin_amdgcn_s_barrier();
    asm volatile("s_waitcnt lgkmcnt(0)" ::: "memory");
    __builtin_amdgcn_sched_barrier(0);
    __builtin_amdgcn_s_setprio(1);
#pragma unroll
    for (int fm = 0; fm < 4; ++fm)
#pragma unroll
      for (int fn = 0; fn < 4; ++fn)
        acc[4 + fm][fn] = __builtin_amdgcn_mfma_f32_16x16x32_bf16(a[fm], b[fn], acc[4 + fm][fn], 0, 0, 0);
    __builtin_amdgcn_s_setprio(0);
    asm volatile("s_waitcnt vmcnt(8)" ::: "memory");
    __builtin_amdgcn_sched_barrier(0);
    __builtin_amdgcn_s_barrier();

    // ---- P2: k-half 1, m-half 0 ----
#pragma unroll
    for (int i = 0; i < 4; ++i) a[i] = rdA(s, 1, i);
#pragma unroll
    for (int i = 0; i < 4; ++i) b[i] = rdB(s, 1, i);
    stage(s, t2c, 0, 0);
    __builtin_amdgcn_s_barrier();
    asm volatile("s_waitcnt lgkmcnt(0)" ::: "memory");
    __builtin_amdgcn_sched_barrier(0);
    __builtin_amdgcn_s_setprio(1);
#pragma unroll
    for (int fm = 0; fm < 4; ++fm)
#pragma unroll
      for (int fn = 0; fn < 4; ++fn)
        acc[fm][fn] = __builtin_amdgcn_mfma_f32_16x16x32_bf16(a[fm], b[fn], acc[fm][fn], 0, 0, 0);
    __builtin_amdgcn_s_setprio(0);
    __builtin_amdgcn_sched_barrier(0);
    __builtin_amdgcn_s_barrier();

    // ---- P3: k-half 1, m-half 1 ----
#pragma unroll
    for (int i = 0; i < 4; ++i) a[i] = rdA(s, 1, 4 + i);
    stage(s, t2c, 1, 0);
    __builtin_amdgcn_s_barrier();
    asm volatile("s_waitcnt lgkmcnt(0)" ::: "memory");
    __builtin_amdgcn_sched_barrier(0);
    __builtin_amdgcn_s_setprio(1);
#pragma unroll
    for (int fm = 0; fm < 4; ++fm)
#pragma unroll
      for (int fn = 0; fn < 4; ++fn)
        acc[4 + fm][fn] = __builtin_amdgcn_mfma_f32_16x16x32_bf16(a[fm], b[fn], acc[4 + fm][fn], 0, 0, 0);
    __builtin_amdgcn_s_setprio(0);
    asm volatile("s_waitcnt vmcnt(8)" ::: "memory");
    __builtin_amdgcn_sched_barrier(0);
    __builtin_amdgcn_s_barrier();
  };

  for (int tt = 0; tt < NT; tt += 2) { tile_body(tt, 0); tile_body(tt + 1, 1); }

  if (EPI == 0) {
#pragma unroll
    for (int fm = 0; fm < 8; ++fm) {
      const long gmb = m0 + wr * 128 + fm * 16 + kg * 4;
#pragma unroll
      for (int fn = 0; fn < 4; ++fn) {
        const long gn = n0 + wc * 64 + fn * 16 + lr;
#pragma unroll
        for (int j = 0; j < 4; ++j)
          Cout[(gmb + j) * (NXT * 256) + gn] = f2bf(acc[fm][fn][j]);
      }
    }
#pragma unroll
    for (int fn = 0; fn < 4; ++fn) {
      const long gn = n0 + wc * 64 + fn * 16 + lr;
      float s = 0.f, q = 0.f;
#pragma unroll
      for (int fm = 0; fm < 8; ++fm) {
        const long gmb = m0 + wr * 128 + fm * 16 + kg * 4;
#pragma unroll
        for (int j = 0; j < 4; ++j) {
          if (gmb + j <= aclamp) {
            const float x = acc[fm][fn][j];
            s += x; q += x * x;
          }
        }
      }
      s += __shfl_xor(s, 16); s += __shfl_xor(s, 32);
      q += __shfl_xor(q, 16); q += __shfl_xor(q, 32);
      if (lane < 16) {
        atomicAdd(faux + gn, s);
        atomicAdd(faux + 768 + gn, q);
      }
    }
  } else {  // EPI == 1
    float bv[4];
#pragma unroll
    for (int fn = 0; fn < 4; ++fn) bv[fn] = bias[n0 + wc * 64 + fn * 16 + lr];
#pragma unroll
    for (int fm = 0; fm < 8; ++fm) {
      const long gmb = m0 + wr * 128 + fm * 16 + kg * 4;
#pragma unroll
      for (int j = 0; j < 4; ++j) {
        const long gm = gmb + j;
        float rs = 0.f;
#pragma unroll
        for (int fn = 0; fn < 4; ++fn) {
          const long gn = n0 + wc * 64 + fn * 16 + lr;
          const float x = acc[fm][fn][j] + bv[fn];
          Cout[gm * (NXT * 256) + gn] = f2bf(x);
          rs += x * x;
        }
        rs += __shfl_xor(rs, 1); rs += __shfl_xor(rs, 2);
        rs += __shfl_xor(rs, 4); rs += __shfl_xor(rs, 8);
        if (lr == 0) atomicAdd(faux + gm, rs);
      }
    }
  }
}

// ---------------------------------------------------------------------------
template<int BLOCK>
__global__ __launch_bounds__(BLOCK)
void rownorm_kernel(const float* __restrict__ in, unsigned short* __restrict__ out,
                    int cols)
{
  __shared__ float red[BLOCK / 64];
  const int row = blockIdx.x, tid = threadIdx.x;
  const int nch = cols / 4;

  float x[4];
  float ss = 0.f;
  if (tid < nch) {
    const f32x4 v = ((const f32x4*)(in + (size_t)row * cols))[tid];
#pragma unroll
    for (int j = 0; j < 4; ++j) { x[j] = v[j]; ss += x[j] * x[j]; }
  }
#pragma unroll
  for (int m = 32; m; m >>= 1) ss += __shfl_xor(ss, m);
  if ((tid & 63) == 0) red[tid >> 6] = ss;
  __syncthreads();
  float tot = 0.f;
#pragma unroll
  for (int i = 0; i < BLOCK / 64; ++i) tot += red[i];
  const float inv = 1.0f / fmaxf(sqrtf(tot), 1e-12f);

  if (tid < nch) {
    __attribute__((ext_vector_type(4))) unsigned short o;
#pragma unroll
    for (int j = 0; j < 4; ++j) o[j] = f2bf(x[j] * inv);
    ((decltype(o)*)(out + (size_t)row * cols))[tid] = o;
  }
}

__global__ __launch_bounds__(256)
void transpose2_kernel(const float* __restrict__ W1, const float* __restrict__ W2,
                       unsigned short* __restrict__ W1T, unsigned short* __restrict__ W2T)
{
  const int i = blockIdx.x * 256 + threadIdx.x;
  if (i < 512 * 768) {
    const int r = i / 768, c = i - r * 768;
    W1T[c * 512 + r] = f2bf(W1[i]);
  } else {
    const int k = i - 512 * 768;
    if (k < 768 * 768) {
      const int r = k / 768, c = k - r * 768;
      W2T[c * 768 + r] = f2bf(W2[k]);
    }
  }
}

__global__ __launch_bounds__(256)
void bnfinal_kernel(const float* __restrict__ sums, const float* __restrict__ gamma,
                    const float* __restrict__ beta, float* __restrict__ sc,
                    float* __restrict__ sh)
{
  const int ch = blockIdx.x * 256 + threadIdx.x;
  if (ch < 768) {
    const float invV = 1.0f / 30000.0f;
    const float mean = sums[ch] * invV;
    const float var  = sums[768 + ch] * invV - mean * mean;
    const float s    = gamma[ch] / sqrtf(var + 1e-5f);
    sc[ch] = s;
    sh[ch] = beta[ch] - mean * s;
  }
}

__global__ __launch_bounds__(256)
void bnapply_kernel(unsigned short* __restrict__ h, const float* __restrict__ sc,
                    const float* __restrict__ sh)
{
  const int total = 30000 * 96;
  for (int c = blockIdx.x * 256 + threadIdx.x; c < total; c += 2048 * 256) {
    const int ch = (c % 96) * 8;
    const u16x8 v = ((const u16x8*)h)[c];
    u16x8 o;
#pragma unroll
    for (int j = 0; j < 8; ++j) {
      const float y = fmaf(bf2f(v[j]), sc[ch + j], sh[ch + j]);
      o[j] = f2bf(fmaxf(y, 0.0f));
    }
    ((u16x8*)h)[c] = o;
  }
}

__global__ __launch_bounds__(256)
void rfin_kernel(const float* __restrict__ rsum, float* __restrict__ rnorm)
{
  const int v = blockIdx.x * 256 + threadIdx.x;
  if (v < 30208) rnorm[v] = 1.0f / fmaxf(sqrtf(rsum[v]), 1e-12f);
}

// Softmax with fixed shift (logits in [-1,1]): S = exp((l-1)*5)
__global__ __launch_bounds__(256)
void smpart_kernel(const unsigned* __restrict__ mk, float* __restrict__ partsum)
{
  __shared__ float red[4];
  const int b = blockIdx.y;
  const unsigned* row = mk + (size_t)b * 30208 + blockIdx.x * 1000;
  float s = 0.f;
  for (int t = threadIdx.x; t < 1000; t += 256)
    s += expf((fdec(row[t]) - 1.0f) * 5.0f);
#pragma unroll
  for (int m = 32; m; m >>= 1) s += __shfl_xor(s, m);
  if ((threadIdx.x & 63) == 0) red[threadIdx.x >> 6] = s;
  __syncthreads();
  if (threadIdx.x == 0)
    atomicAdd(partsum + b, red[0] + red[1] + red[2] + red[3]);
}

__global__ __launch_bounds__(256)
void smfinal_kernel(const unsigned* __restrict__ mk, const float* __restrict__ partsum,
                    float* __restrict__ out)
{
  const int b = blockIdx.y;
  const int c = blockIdx.x * 256 + threadIdx.x;
  if (c < 3750) {
    const unsigned* row = mk + (size_t)b * 30208 + c * 8;
    const float inv = 1.0f / partsum[b];
    const u32x4 k0 = *(const u32x4*)row;
    const u32x4 k1 = *(const u32x4*)(row + 4);
    f32x4 o0, o1;
#pragma unroll
    for (int j = 0; j < 4; ++j) {
      o0[j] = expf((fdec(k0[j]) - 1.0f) * 5.0f) * inv;
      o1[j] = expf((fdec(k1[j]) - 1.0f) * 5.0f) * inv;
    }
    float* op = out + (size_t)b * 30000 + c * 8;
    *(f32x4*)op = o0;
    *(f32x4*)(op + 4) = o1;
  }
}

extern "C" void kernel_launch(void* const* d_in, const int* in_sizes, int n_in,
                              void* d_out, int out_size, void* d_ws, size_t ws_size,
                              hipStream_t stream)
{
  (void)in_sizes; (void)n_in; (void)out_size; (void)ws_size;
  const float* patch = (const float*)d_in[0];   // [8,1024,768]
  const float* vocab = (const float*)d_in[1];   // [30000,512]
  const float* W1    = (const float*)d_in[2];   // [512,768]
  const float* gamma = (const float*)d_in[3];   // [768]
  const float* beta  = (const float*)d_in[4];   // [768]
  const float* W2    = (const float*)d_in[5];   // [768,768]
  const float* b2    = (const float*)d_in[6];   // [768]
  float* out = (float*)d_out;                   // [8,30000]

  char* ws = (char*)d_ws;
  size_t off = 0;
  auto alloc = [&](size_t bytes) {
    char* p = ws + off;
    off += (bytes + 1023) & ~(size_t)1023;
    return p;
  };
  unsigned short* vocab_n = (unsigned short*)alloc(30000ull * 512 * 2);
  unsigned short* pt_n    = (unsigned short*)alloc(8192ull * 768 * 2);
  unsigned short* W1T     = (unsigned short*)alloc(768ull * 512 * 2);
  unsigned short* W2T     = (unsigned short*)alloc(768ull * 768 * 2);
  unsigned short* hbuf    = (unsigned short*)alloc(30208ull * 768 * 2);  // padded M
  unsigned short* pbuf    = (unsigned short*)alloc(30208ull * 768 * 2);  // padded M
  // contiguous zeroed region: bnsums(1536) | rsum(30208) | partsum(8) | maxkey(8*30208)
  float* zbase = (float*)alloc((1536ull + 30208 + 8 + 8ull * 30208) * 4);
  float*    bnsums  = zbase;
  float*    rsum    = zbase + 1536;
  float*    partsum = zbase + 1536 + 30208;
  unsigned* maxkey  = (unsigned*)(zbase + 1536 + 30208 + 8);
  float*    bnsc    = (float*)alloc(768ull * 4);
  float*    bnsh    = (float*)alloc(768ull * 4);
  float*    rnorm   = (float*)alloc(30208ull * 4);

  hipMemsetAsync(zbase, 0, (1536ull + 30208 + 8 + 8ull * 30208) * 4, stream);

  transpose2_kernel<<<CDIV(512 * 768 + 768 * 768, 256), 256, 0, stream>>>(W1, W2, W1T, W2T);
  rownorm_kernel<256><<<30000, 256, 0, stream>>>(vocab, vocab_n, 512);
  rownorm_kernel<256><<<8192, 256, 0, stream>>>(patch, pt_n, 768);

  // h = vocab_n @ W1 (K=512) with fused BN stats; M padded to 30208
  gemm8p_kernel<8, 3, 0><<<354, 512, 0, stream>>>(
      vocab_n, W1T, hbuf, nullptr, bnsums, 29999);
  bnfinal_kernel<<<3, 256, 0, stream>>>(bnsums, gamma, beta, bnsc, bnsh);
  bnapply_kernel<<<2048, 256, 0, stream>>>(hbuf, bnsc, bnsh);

  // p = h_bn @ W2 + b2 (K=768) with fused per-row sumsq
  gemm8p_kernel<12, 3, 1><<<354, 512, 0, stream>>>(
      hbuf, W2T, pbuf, b2, rsum, 30207);
  rfin_kernel<<<118, 256, 0, stream>>>(rsum, rnorm);

  // logits+max over patches, 32x32x16 MFMA; normalization folded in via rnorm
  gemm8p32_kernel<12, 118, 472><<<3776, 512, 0, stream>>>(
      pt_n, pbuf, rnorm, maxkey);

  smpart_kernel<<<dim3(30, 8), 256, 0, stream>>>(maxkey, partsum);
  smfinal_kernel<<<dim3(15, 8), 256, 0, stream>>>(maxkey, partsum, out);
}

// Round 7
// 623.749 us; speedup vs baseline: 1.0604x; 1.0604x over previous
//
#include <hip/hip_runtime.h>
#include <hip/hip_bf16.h>
#include <cstdint>

// patch_tokens [8,1024,768] f32, vocab [30000,512] f32, W1 [512,768], gamma/beta [768],
// W2 [768,768], b2 [768]  ->  out [8,30000] f32 (softmax mixture weights)

#define CDIV(a,b) (((a)+(b)-1)/(b))

using bf16x8 = __attribute__((ext_vector_type(8))) __bf16;
using f32x4  = __attribute__((ext_vector_type(4))) float;
using u16x8  = __attribute__((ext_vector_type(8))) unsigned short;
using u32x4  = __attribute__((ext_vector_type(4))) unsigned;

__device__ __forceinline__ unsigned short f2bf(float x) {
  unsigned u = __float_as_uint(x);
  u += 0x7fffu + ((u >> 16) & 1u);          // round-to-nearest-even
  return (unsigned short)(u >> 16);
}
__device__ __forceinline__ float bf2f(unsigned short b) {
  return __uint_as_float(((unsigned)b) << 16);
}
// order-preserving float<->uint key for atomicMax
__device__ __forceinline__ unsigned fkey(float x) {
  unsigned u = __float_as_uint(x);
  return (u & 0x80000000u) ? ~u : (u | 0x80000000u);
}
__device__ __forceinline__ float fdec(unsigned k) {
  unsigned u = (k & 0x80000000u) ? (k ^ 0x80000000u) : ~k;
  return __uint_as_float(u);
}

// ---------------------------------------------------------------------------
// BIG GEMM: 256x256 tile, 16x16x32 MFMA, 8-phase counted-vmcnt schedule.
// Verbatim the verified R2/R3/R5 body (0 bank conflicts, ~46-48% MfmaUtil),
// standalone (not template-shared) to decouple codegen. K=768, NXT=118,
// bijective XCD swizzle for grid 3776 = 8*472.
// Epilogue: column max over 256 rows * rnorm[col] -> atomicMax maxk[b][col].
// ---------------------------------------------------------------------------
__global__ __launch_bounds__(512, 1)
void gbig_kernel(const unsigned short* __restrict__ A,
                 const unsigned short* __restrict__ B,
                 const float* __restrict__ rnorm,
                 unsigned* __restrict__ maxk)
{
  constexpr int K = 768, NT = 12, NXT = 118;
  __shared__ __align__(16) unsigned short lds[8 * 8192];  // 128 KiB

  const int tid = threadIdx.x;
  const int w = tid >> 6, lane = tid & 63;
  const int lr = lane & 15, kg = lane >> 4;
  const int wr = w >> 2, wc = w & 3;

  const int bid = blockIdx.x;
  const int wg = (bid & 7) * 472 + (bid >> 3);
  const long m0 = (long)(wg / NXT) * 256;
  const long n0 = (long)(wg % NXT) * 256;

  auto stage = [&](int slot, int tk, int mat, int h) {
    const unsigned short* src = mat ? B : A;
    const long row0 = mat ? n0 : m0;
    unsigned short* dst = lds + (((slot * 2) + mat) * 2 + h) * 8192;
#pragma unroll
    for (int ld = 0; ld < 2; ++ld) {
      const int lc  = ld * 512 + tid;
      const long row = row0 + (lc >> 2);
      const int qc  = (lc & 3) ^ (((lc >> 2) >> 1) & 3);
      const unsigned short* gp = src + row * K + tk * 64 + h * 32 + qc * 8;
      __builtin_amdgcn_global_load_lds(
          (const __attribute__((address_space(1))) void*)gp,
          (__attribute__((address_space(3))) void*)(dst + (ld * 512 + (w << 6)) * 8),
          16, 0, 0);
    }
  };
  auto rdA = [&](int s, int h, int fm) -> bf16x8 {
    const int row = wr * 128 + fm * 16 + lr;
    const int pc  = kg ^ ((row >> 1) & 3);
    return *(const bf16x8*)(lds + ((s * 2 + 0) * 2 + h) * 8192 + row * 32 + pc * 8);
  };
  auto rdB = [&](int s, int h, int fn) -> bf16x8 {
    const int row = wc * 64 + fn * 16 + lr;
    const int pc  = kg ^ ((row >> 1) & 3);
    return *(const bf16x8*)(lds + ((s * 2 + 1) * 2 + h) * 8192 + row * 32 + pc * 8);
  };

  f32x4 acc[8][4];
#pragma unroll
  for (int i = 0; i < 8; ++i)
#pragma unroll
    for (int j = 0; j < 4; ++j) acc[i][j] = f32x4{0.f, 0.f, 0.f, 0.f};

  stage(0, 0, 0, 0); stage(0, 0, 1, 0); stage(0, 0, 0, 1);
  stage(0, 0, 1, 1); stage(1, 1, 0, 0); stage(1, 1, 1, 0);
  asm volatile("s_waitcnt vmcnt(8)" ::: "memory");
  __builtin_amdgcn_s_barrier();

  bf16x8 a[4], b[4];
  auto tile_body = [&](int t, int s) {
    const int t1c = (t + 1 < NT) ? t + 1 : NT - 1;
    const int t2c = (t + 2 < NT) ? t + 2 : NT - 1;
    const int s1  = s ^ 1;

    // ---- P0: k-half 0, m-half 0 ----
#pragma unroll
    for (int i = 0; i < 4; ++i) a[i] = rdA(s, 0, i);
#pragma unroll
    for (int i = 0; i < 4; ++i) b[i] = rdB(s, 0, i);
    stage(s1, t1c, 0, 1);
    __builtin_amdgcn_s_barrier();
    asm volatile("s_waitcnt lgkmcnt(0)" ::: "memory");
    __builtin_amdgcn_sched_barrier(0);
    __builtin_amdgcn_s_setprio(1);
#pragma unroll
    for (int fm = 0; fm < 4; ++fm)
#pragma unroll
      for (int fn = 0; fn < 4; ++fn)
        acc[fm][fn] = __builtin_amdgcn_mfma_f32_16x16x32_bf16(a[fm], b[fn], acc[fm][fn], 0, 0, 0);
    __builtin_amdgcn_s_setprio(0);
    __builtin_amdgcn_sched_barrier(0);
    __builtin_amdgcn_s_barrier();

    // ---- P1: k-half 0, m-half 1 ----
#pragma unroll
    for (int i = 0; i < 4; ++i) a[i] = rdA(s, 0, 4 + i);
    stage(s1, t1c, 1, 1);
    __builtin_amdgcn_s_barrier();
    asm volatile("s_waitcnt lgkmcnt(0)" ::: "memory");
    __builtin_amdgcn_sched_barrier(0);
    __builtin_amdgcn_s_setprio(1);
#pragma unroll
    for (int fm = 0; fm < 4; ++fm)
#pragma unroll
      for (int fn = 0; fn < 4; ++fn)
        acc[4 + fm][fn] = __builtin_amdgcn_mfma_f32_16x16x32_bf16(a[fm], b[fn], acc[4 + fm][fn], 0, 0, 0);
    __builtin_amdgcn_s_setprio(0);
    asm volatile("s_waitcnt vmcnt(8)" ::: "memory");
    __builtin_amdgcn_sched_barrier(0);
    __builtin_amdgcn_s_barrier();

    // ---- P2: k-half 1, m-half 0 ----
#pragma unroll
    for (int i = 0; i < 4; ++i) a[i] = rdA(s, 1, i);
#pragma unroll
    for (int i = 0; i < 4; ++i) b[i] = rdB(s, 1, i);
    stage(s, t2c, 0, 0);
    __builtin_amdgcn_s_barrier();
    asm volatile("s_waitcnt lgkmcnt(0)" ::: "memory");
    __builtin_amdgcn_sched_barrier(0);
    __builtin_amdgcn_s_setprio(1);
#pragma unroll
    for (int fm = 0; fm < 4; ++fm)
#pragma unroll
      for (int fn = 0; fn < 4; ++fn)
        acc[fm][fn] = __builtin_amdgcn_mfma_f32_16x16x32_bf16(a[fm], b[fn], acc[fm][fn], 0, 0, 0);
    __builtin_amdgcn_s_setprio(0);
    __builtin_amdgcn_sched_barrier(0);
    __builtin_amdgcn_s_barrier();

    // ---- P3: k-half 1, m-half 1 ----
#pragma unroll
    for (int i = 0; i < 4; ++i) a[i] = rdA(s, 1, 4 + i);
    stage(s, t2c, 1, 0);
    __builtin_amdgcn_s_barrier();
    asm volatile("s_waitcnt lgkmcnt(0)" ::: "memory");
    __builtin_amdgcn_sched_barrier(0);
    __builtin_amdgcn_s_setprio(1);
#pragma unroll
    for (int fm = 0; fm < 4; ++fm)
#pragma unroll
      for (int fn = 0; fn < 4; ++fn)
        acc[4 + fm][fn] = __builtin_amdgcn_mfma_f32_16x16x32_bf16(a[fm], b[fn], acc[4 + fm][fn], 0, 0, 0);
    __builtin_amdgcn_s_setprio(0);
    asm volatile("s_waitcnt vmcnt(8)" ::: "memory");
    __builtin_amdgcn_sched_barrier(0);
    __builtin_amdgcn_s_barrier();
  };

  for (int tt = 0; tt < NT; tt += 2) { tile_body(tt, 0); tile_body(tt + 1, 1); }

  const int bb = (int)(m0 >> 10);
#pragma unroll
  for (int fn = 0; fn < 4; ++fn) {
    float mx = acc[0][fn][0];
#pragma unroll
    for (int fm = 0; fm < 8; ++fm)
#pragma unroll
      for (int j = 0; j < 4; ++j) mx = fmaxf(mx, acc[fm][fn][j]);
    mx = fmaxf(mx, __shfl_xor(mx, 16));
    mx = fmaxf(mx, __shfl_xor(mx, 32));
    const long gn = n0 + wc * 64 + fn * 16 + lr;
    if (lane < 16)
      atomicMax(maxk + (long)bb * 30208 + gn, fkey(mx * rnorm[gn]));
  }
}

// ---------------------------------------------------------------------------
// Small GEMM: 128x256 tile, 16x16x32 MFMA, 2 phases/K-tile, counted vmcnt(6).
// Grid 236x3 = 708 blocks (vs 354) halves the round-quantization idle tail.
// LDS 96KB: A regions (slot,kh) 4x8KB @ 0, B regions 4x16KB @ 32KB.
// Per phase: 8 ds_read_b128 + stageA(1 load) + stageB(2 loads) + 16 MFMA.
// vmcnt(6) derivation: steady-state in-flight = {t.k1, (t+1).k0} = 2x3 loads.
// EPI 0: store bf16 C + fused BN column stats (guard gm<=aclamp)
// EPI 1: store bf16 (C+bias) + fused per-row sumsq -> atomicAdd faux[row]
// ---------------------------------------------------------------------------
template<int NT, int EPI>
__global__ __launch_bounds__(512, 1)
void gemm128_kernel(const unsigned short* __restrict__ A,
                    const unsigned short* __restrict__ B,
                    unsigned short* __restrict__ Cout,
                    const float* __restrict__ bias,
                    float* __restrict__ faux,
                    int aclamp)
{
  constexpr int K = NT * 64;
  __shared__ __align__(16) unsigned short lds[49152];  // 96 KiB

  const int tid = threadIdx.x;
  const int w = tid >> 6, lane = tid & 63;
  const int lr = lane & 15, kg = lane >> 4;
  const int wr = w >> 2, wc = w & 3;          // 2m x 4n wave grid, 64x64 each

  const int wg = blockIdx.x;
  const long m0 = (long)(wg / 3) * 128;
  const long n0 = (long)(wg % 3) * 256;

  auto stageA = [&](int slot, int tk, int h) {
    unsigned short* dst = lds + (slot * 2 + h) * 4096;
    long row = m0 + (tid >> 2);
    if (row > aclamp) row = aclamp;
    const int qc = (tid & 3) ^ ((tid >> 3) & 3);
    const unsigned short* gp = A + row * K + tk * 64 + h * 32 + qc * 8;
    __builtin_amdgcn_global_load_lds(
        (const __attribute__((address_space(1))) void*)gp,
        (__attribute__((address_space(3))) void*)(dst + (w << 6) * 8), 16, 0, 0);
  };
  auto stageB = [&](int slot, int tk, int h) {
    unsigned short* dst = lds + 16384 + (slot * 2 + h) * 8192;
#pragma unroll
    for (int ld = 0; ld < 2; ++ld) {
      const int lc = ld * 512 + tid;
      const long row = n0 + (lc >> 2);
      const int qc = (lc & 3) ^ (((lc >> 2) >> 1) & 3);
      const unsigned short* gp = B + row * K + tk * 64 + h * 32 + qc * 8;
      __builtin_amdgcn_global_load_lds(
          (const __attribute__((address_space(1))) void*)gp,
          (__attribute__((address_space(3))) void*)(dst + (ld * 512 + (w << 6)) * 8),
          16, 0, 0);
    }
  };
  auto rdA = [&](int s, int h, int fm) -> bf16x8 {
    const int row = wr * 64 + fm * 16 + lr;
    const int pc  = kg ^ ((row >> 1) & 3);
    return *(const bf16x8*)(lds + (s * 2 + h) * 4096 + row * 32 + pc * 8);
  };
  auto rdB = [&](int s, int h, int fn) -> bf16x8 {
    const int row = wc * 64 + fn * 16 + lr;
    const int pc  = kg ^ ((row >> 1) & 3);
    return *(const bf16x8*)(lds + 16384 + (s * 2 + h) * 8192 + row * 32 + pc * 8);
  };

  f32x4 acc[4][4];
#pragma unroll
  for (int i = 0; i < 4; ++i)
#pragma unroll
    for (int j = 0; j < 4; ++j) acc[i][j] = f32x4{0.f, 0.f, 0.f, 0.f};

  // prologue: t0.k0, t0.k1, t1.k0 (9 loads); vmcnt(6) -> t0.k0 landed
  stageA(0, 0, 0); stageB(0, 0, 0);
  stageA(0, 0, 1); stageB(0, 0, 1);
  stageA(1, 1, 0); stageB(1, 1, 0);
  asm volatile("s_waitcnt vmcnt(6)" ::: "memory");
  __builtin_amdgcn_s_barrier();

  bf16x8 a[4], b[4];
  auto phase = [&](int s, int h, int st_slot, int st_tk, int st_h) {
#pragma unroll
    for (int i = 0; i < 4; ++i) a[i] = rdA(s, h, i);
#pragma unroll
    for (int i = 0; i < 4; ++i) b[i] = rdB(s, h, i);
    stageA(st_slot, st_tk, st_h);
    stageB(st_slot, st_tk, st_h);
    __builtin_amdgcn_s_barrier();
    asm volatile("s_waitcnt lgkmcnt(0)" ::: "memory");
    __builtin_amdgcn_sched_barrier(0);
    __builtin_amdgcn_s_setprio(1);
#pragma unroll
    for (int fm = 0; fm < 4; ++fm)
#pragma unroll
      for (int fn = 0; fn < 4; ++fn)
        acc[fm][fn] = __builtin_amdgcn_mfma_f32_16x16x32_bf16(a[fm], b[fn], acc[fm][fn], 0, 0, 0);
    __builtin_amdgcn_s_setprio(0);
    asm volatile("s_waitcnt vmcnt(6)" ::: "memory");
    __builtin_amdgcn_sched_barrier(0);
    __builtin_amdgcn_s_barrier();
  };

  for (int t = 0; t < NT; ++t) {
    const int s = t & 1;
    const int t1c = (t + 1 < NT) ? t + 1 : NT - 1;
    const int t2c = (t + 2 < NT) ? t + 2 : NT - 1;
    phase(s, 0, s ^ 1, t1c, 1);   // stage (t+1).k1 into other slot
    phase(s, 1, s, t2c, 0);       // stage (t+2).k0 into this slot (k0 reads done)
  }

  if (EPI == 0) {
#pragma unroll
    for (int fm = 0; fm < 4; ++fm) {
      const long gmb = m0 + wr * 64 + fm * 16 + kg * 4;
#pragma unroll
      for (int fn = 0; fn < 4; ++fn) {
        const long gn = n0 + wc * 64 + fn * 16 + lr;
#pragma unroll
        for (int j = 0; j < 4; ++j)
          Cout[(gmb + j) * 768 + gn] = f2bf(acc[fm][fn][j]);
      }
    }
#pragma unroll
    for (int fn = 0; fn < 4; ++fn) {
      const long gn = n0 + wc * 64 + fn * 16 + lr;
      float s = 0.f, q = 0.f;
#pragma unroll
      for (int fm = 0; fm < 4; ++fm) {
        const long gmb = m0 + wr * 64 + fm * 16 + kg * 4;
#pragma unroll
        for (int j = 0; j < 4; ++j) {
          if (gmb + j <= aclamp) {
            const float x = acc[fm][fn][j];
            s += x; q += x * x;
          }
        }
      }
      s += __shfl_xor(s, 16); s += __shfl_xor(s, 32);
      q += __shfl_xor(q, 16); q += __shfl_xor(q, 32);
      if (lane < 16) {
        atomicAdd(faux + gn, s);
        atomicAdd(faux + 768 + gn, q);
      }
    }
  } else {
    float bv[4];
#pragma unroll
    for (int fn = 0; fn < 4; ++fn) bv[fn] = bias[n0 + wc * 64 + fn * 16 + lr];
#pragma unroll
    for (int fm = 0; fm < 4; ++fm) {
      const long gmb = m0 + wr * 64 + fm * 16 + kg * 4;
#pragma unroll
      for (int j = 0; j < 4; ++j) {
        const long gm = gmb + j;
        float rs = 0.f;
#pragma unroll
        for (int fn = 0; fn < 4; ++fn) {
          const long gn = n0 + wc * 64 + fn * 16 + lr;
          const float x = acc[fm][fn][j] + bv[fn];
          Cout[gm * 768 + gn] = f2bf(x);
          rs += x * x;
        }
        rs += __shfl_xor(rs, 1); rs += __shfl_xor(rs, 2);
        rs += __shfl_xor(rs, 4); rs += __shfl_xor(rs, 8);
        if (lr == 0) atomicAdd(faux + gm, rs);
      }
    }
  }
}

// ---------------------------------------------------------------------------
template<int BLOCK>
__global__ __launch_bounds__(BLOCK)
void rownorm_kernel(const float* __restrict__ in, unsigned short* __restrict__ out,
                    int cols)
{
  __shared__ float red[BLOCK / 64];
  const int row = blockIdx.x, tid = threadIdx.x;
  const int nch = cols / 4;

  float x[4];
  float ss = 0.f;
  if (tid < nch) {
    const f32x4 v = ((const f32x4*)(in + (size_t)row * cols))[tid];
#pragma unroll
    for (int j = 0; j < 4; ++j) { x[j] = v[j]; ss += x[j] * x[j]; }
  }
#pragma unroll
  for (int m = 32; m; m >>= 1) ss += __shfl_xor(ss, m);
  if ((tid & 63) == 0) red[tid >> 6] = ss;
  __syncthreads();
  float tot = 0.f;
#pragma unroll
  for (int i = 0; i < BLOCK / 64; ++i) tot += red[i];
  const float inv = 1.0f / fmaxf(sqrtf(tot), 1e-12f);

  if (tid < nch) {
    __attribute__((ext_vector_type(4))) unsigned short o;
#pragma unroll
    for (int j = 0; j < 4; ++j) o[j] = f2bf(x[j] * inv);
    ((decltype(o)*)(out + (size_t)row * cols))[tid] = o;
  }
}

__global__ __launch_bounds__(256)
void transpose2_kernel(const float* __restrict__ W1, const float* __restrict__ W2,
                       unsigned short* __restrict__ W1T, unsigned short* __restrict__ W2T)
{
  const int i = blockIdx.x * 256 + threadIdx.x;
  if (i < 512 * 768) {
    const int r = i / 768, c = i - r * 768;
    W1T[c * 512 + r] = f2bf(W1[i]);
  } else {
    const int k = i - 512 * 768;
    if (k < 768 * 768) {
      const int r = k / 768, c = k - r * 768;
      W2T[c * 768 + r] = f2bf(W2[k]);
    }
  }
}

__global__ __launch_bounds__(256)
void bnfinal_kernel(const float* __restrict__ sums, const float* __restrict__ gamma,
                    const float* __restrict__ beta, float* __restrict__ sc,
                    float* __restrict__ sh)
{
  const int ch = blockIdx.x * 256 + threadIdx.x;
  if (ch < 768) {
    const float invV = 1.0f / 30000.0f;
    const float mean = sums[ch] * invV;
    const float var  = sums[768 + ch] * invV - mean * mean;
    const float s    = gamma[ch] / sqrtf(var + 1e-5f);
    sc[ch] = s;
    sh[ch] = beta[ch] - mean * s;
  }
}

__global__ __launch_bounds__(256)
void bnapply_kernel(unsigned short* __restrict__ h, const float* __restrict__ sc,
                    const float* __restrict__ sh)
{
  const int total = 30000 * 96;
  for (int c = blockIdx.x * 256 + threadIdx.x; c < total; c += 2048 * 256) {
    const int ch = (c % 96) * 8;
    const u16x8 v = ((const u16x8*)h)[c];
    u16x8 o;
#pragma unroll
    for (int j = 0; j < 8; ++j) {
      const float y = fmaf(bf2f(v[j]), sc[ch + j], sh[ch + j]);
      o[j] = f2bf(fmaxf(y, 0.0f));
    }
    ((u16x8*)h)[c] = o;
  }
}

__global__ __launch_bounds__(256)
void rfin_kernel(const float* __restrict__ rsum, float* __restrict__ rnorm)
{
  const int v = blockIdx.x * 256 + threadIdx.x;
  if (v < 30208) rnorm[v] = 1.0f / fmaxf(sqrtf(rsum[v]), 1e-12f);
}

// Softmax with fixed shift (logits in [-1,1]): S = exp((l-1)*5)
__global__ __launch_bounds__(256)
void smpart_kernel(const unsigned* __restrict__ mk, float* __restrict__ partsum)
{
  __shared__ float red[4];
  const int b = blockIdx.y;
  const unsigned* row = mk + (size_t)b * 30208 + blockIdx.x * 1000;
  float s = 0.f;
  for (int t = threadIdx.x; t < 1000; t += 256)
    s += expf((fdec(row[t]) - 1.0f) * 5.0f);
#pragma unroll
  for (int m = 32; m; m >>= 1) s += __shfl_xor(s, m);
  if ((threadIdx.x & 63) == 0) red[threadIdx.x >> 6] = s;
  __syncthreads();
  if (threadIdx.x == 0)
    atomicAdd(partsum + b, red[0] + red[1] + red[2] + red[3]);
}

__global__ __launch_bounds__(256)
void smfinal_kernel(const unsigned* __restrict__ mk, const float* __restrict__ partsum,
                    float* __restrict__ out)
{
  const int b = blockIdx.y;
  const int c = blockIdx.x * 256 + threadIdx.x;
  if (c < 3750) {
    const unsigned* row = mk + (size_t)b * 30208 + c * 8;
    const float inv = 1.0f / partsum[b];
    const u32x4 k0 = *(const u32x4*)row;
    const u32x4 k1 = *(const u32x4*)(row + 4);
    f32x4 o0, o1;
#pragma unroll
    for (int j = 0; j < 4; ++j) {
      o0[j] = expf((fdec(k0[j]) - 1.0f) * 5.0f) * inv;
      o1[j] = expf((fdec(k1[j]) - 1.0f) * 5.0f) * inv;
    }
    float* op = out + (size_t)b * 30000 + c * 8;
    *(f32x4*)op = o0;
    *(f32x4*)(op + 4) = o1;
  }
}

extern "C" void kernel_launch(void* const* d_in, const int* in_sizes, int n_in,
                              void* d_out, int out_size, void* d_ws, size_t ws_size,
                              hipStream_t stream)
{
  (void)in_sizes; (void)n_in; (void)out_size; (void)ws_size;
  const float* patch = (const float*)d_in[0];   // [8,1024,768]
  const float* vocab = (const float*)d_in[1];   // [30000,512]
  const float* W1    = (const float*)d_in[2];   // [512,768]
  const float* gamma = (const float*)d_in[3];   // [768]
  const float* beta  = (const float*)d_in[4];   // [768]
  const float* W2    = (const float*)d_in[5];   // [768,768]
  const float* b2    = (const float*)d_in[6];   // [768]
  float* out = (float*)d_out;                   // [8,30000]

  char* ws = (char*)d_ws;
  size_t off = 0;
  auto alloc = [&](size_t bytes) {
    char* p = ws + off;
    off += (bytes + 1023) & ~(size_t)1023;
    return p;
  };
  unsigned short* vocab_n = (unsigned short*)alloc(30000ull * 512 * 2);
  unsigned short* pt_n    = (unsigned short*)alloc(8192ull * 768 * 2);
  unsigned short* W1T     = (unsigned short*)alloc(768ull * 512 * 2);
  unsigned short* W2T     = (unsigned short*)alloc(768ull * 768 * 2);
  unsigned short* hbuf    = (unsigned short*)alloc(30208ull * 768 * 2);  // padded M
  unsigned short* pbuf    = (unsigned short*)alloc(30208ull * 768 * 2);  // padded M
  // contiguous zeroed region: bnsums(1536) | rsum(30208) | partsum(8) | maxkey(8*30208)
  float* zbase = (float*)alloc((1536ull + 30208 + 8 + 8ull * 30208) * 4);
  float*    bnsums  = zbase;
  float*    rsum    = zbase + 1536;
  float*    partsum = zbase + 1536 + 30208;
  unsigned* maxkey  = (unsigned*)(zbase + 1536 + 30208 + 8);
  float*    bnsc    = (float*)alloc(768ull * 4);
  float*    bnsh    = (float*)alloc(768ull * 4);
  float*    rnorm   = (float*)alloc(30208ull * 4);

  hipMemsetAsync(zbase, 0, (1536ull + 30208 + 8 + 8ull * 30208) * 4, stream);

  transpose2_kernel<<<CDIV(512 * 768 + 768 * 768, 256), 256, 0, stream>>>(W1, W2, W1T, W2T);
  rownorm_kernel<256><<<30000, 256, 0, stream>>>(vocab, vocab_n, 512);
  rownorm_kernel<256><<<8192, 256, 0, stream>>>(patch, pt_n, 768);

  // h = vocab_n @ W1 (K=512) with fused BN stats; 128x256 tiles, grid 708
  gemm128_kernel<8, 0><<<708, 512, 0, stream>>>(
      vocab_n, W1T, hbuf, nullptr, bnsums, 29999);
  bnfinal_kernel<<<3, 256, 0, stream>>>(bnsums, gamma, beta, bnsc, bnsh);
  bnapply_kernel<<<2048, 256, 0, stream>>>(hbuf, bnsc, bnsh);

  // p = h_bn @ W2 + b2 (K=768) with fused per-row sumsq; grid 708
  gemm128_kernel<12, 1><<<708, 512, 0, stream>>>(
      hbuf, W2T, pbuf, b2, rsum, 30207);
  rfin_kernel<<<118, 256, 0, stream>>>(rsum, rnorm);

  // logits + max over patches (16x16x32, verified schedule), rnorm folded in
  gbig_kernel<<<3776, 512, 0, stream>>>(pt_n, pbuf, rnorm, maxkey);

  smpart_kernel<<<dim3(30, 8), 256, 0, stream>>>(maxkey, partsum);
  smfinal_kernel<<<dim3(15, 8), 256, 0, stream>>>(maxkey, partsum, out);
}